// Round 8
// baseline (3028.413 us; speedup 1.0000x reference)
//
#include <hip/hip_runtime.h>

// Problem constants (match reference)
#define BATCH 4
#define SLEN  4096
#define DIMK  4096
#define HD    512
#define RD    64
#define NCOLS 2048          // [kv(1024) | sc(1024)]
#define MROWS (BATCH*SLEN)  // 16384

typedef __attribute__((ext_vector_type(8))) short bf16x8;
typedef __attribute__((ext_vector_type(4))) float f32x4;
typedef unsigned short u16;

// ---------- bf16 helpers ----------
__device__ inline u16 f2b(float f) {
  union { float f; unsigned u; } x; x.f = f;
  unsigned r = (x.u + 0x7fffu + ((x.u >> 16) & 1u)) >> 16;
  return (u16)r;
}
__device__ inline float b2f(u16 u) {
  union { float f; unsigned u; } x; x.u = ((unsigned)u) << 16; return x.f;
}

#define GLL16(gp, lp) __builtin_amdgcn_global_load_lds( \
    (__attribute__((address_space(1))) void*)(gp),      \
    (__attribute__((address_space(3))) void*)(lp), 16, 0, 0)

// ---------- kernel 1: x (f32) -> bf16 ----------
__global__ __launch_bounds__(256) void cvt_x_kernel(const float4* __restrict__ x,
                                                    u16* __restrict__ xb) {
  size_t i = (size_t)blockIdx.x * 256 + threadIdx.x;
  float4 a = x[2 * i], b = x[2 * i + 1];
  bf16x8 v;
  v[0] = (short)f2b(a.x); v[1] = (short)f2b(a.y);
  v[2] = (short)f2b(a.z); v[3] = (short)f2b(a.w);
  v[4] = (short)f2b(b.x); v[5] = (short)f2b(b.y);
  v[6] = (short)f2b(b.z); v[7] = (short)f2b(b.w);
  *(bf16x8*)(xb + i * 8) = v;
}

// ---------- kernel 2: Wt[n][k] = [wkv|wgate][k][n] as bf16 ----------
__global__ __launch_bounds__(256) void build_wt_kernel(const float* __restrict__ wkv,
                                                       const float* __restrict__ wg,
                                                       u16* __restrict__ Wt) {
  __shared__ u16 tile[64][72];
  const int n0 = blockIdx.x * 64;
  const int k0 = blockIdx.y * 64;
  const float* src = (n0 < 1024) ? wkv : wg;
  const int nbase = (n0 < 1024) ? n0 : (n0 - 1024);
  const int t = threadIdx.x;
  const int nn = t & 63, kq = t >> 6;
  #pragma unroll
  for (int j = 0; j < 16; ++j) {
    int k = kq + j * 4;
    float v = src[(size_t)(k0 + k) * 1024 + nbase + nn];
    tile[nn][k] = f2b(v);
  }
  __syncthreads();
  const int kk8 = (t & 7) * 8;
  #pragma unroll
  for (int j = 0; j < 2; ++j) {
    int nn2 = (t >> 3) + j * 32;
    bf16x8 v = *(bf16x8*)&tile[nn2][kk8];
    *(bf16x8*)&Wt[(size_t)(n0 + nn2) * DIMK + k0 + kk8] = v;
  }
}

// ---------- kernel 3: GEMM 256x256, BK=64, 4-phase/tile, 1 barrier/phase ----------
// Templated ablation probe (R8):
//   VAR=0: full (ds_reads + MFMA)          — NTRUN=64 is the correct kernel
//   VAR=1: stage+vmcnt+barriers only        — isolates global->LDS delivery
//   VAR=2: stage+reads, MFMA -> asm keepalive — adds LDS-read path
// Probes run NTRUN=256 (reads run past K into adjacent ws regions — in-bounds
// of d_ws, garbage data, output overwritten by the final VAR=0 dispatch).
template <int VAR, int NTRUN>
__global__ __launch_bounds__(512, 2) void gemm_probe(const u16* __restrict__ A,
                                                     const u16* __restrict__ Bt,
                                                     u16* __restrict__ C) {
  __shared__ __align__(16) u16 Asm[2][8][256][8];   // 64 KiB
  __shared__ __align__(16) u16 Bsm[2][8][256][8];   // 64 KiB
  const int t = threadIdx.x;
  const int lane = t & 63, wave = t >> 6;

  const int orig = blockIdx.x;
  const int lid = (orig & 7) * 64 + (orig >> 3);
  const int mt = lid >> 3, nt = lid & 7;
  const int m0 = mt * 256, n0 = nt * 256;
  const int wr = wave >> 2, wc = wave & 3;          // 2M x 4N waves

  f32x4 acc[8][4] = {};

  const int rowS = t & 255, kcS = t >> 8;
  const u16* gA = A  + (size_t)(m0 + rowS) * DIMK;
  const u16* gB = Bt + (size_t)(n0 + rowS) * DIMK;

#define SA(buf, tt, kh) do {                                                  \
    GLL16(gA + (tt) * 64 + (kh) * 32 + kcS * 8,                               \
          &Asm[buf][(kh) * 4 + kcS][rowS][0]);                                \
    GLL16(gA + (tt) * 64 + (kh) * 32 + (2 + kcS) * 8,                         \
          &Asm[buf][(kh) * 4 + 2 + kcS][rowS][0]);                            \
  } while (0)
#define SB(buf, tt, kh) do {                                                  \
    GLL16(gB + (tt) * 64 + (kh) * 32 + kcS * 8,                               \
          &Bsm[buf][(kh) * 4 + kcS][rowS][0]);                                \
    GLL16(gB + (tt) * 64 + (kh) * 32 + (2 + kcS) * 8,                         \
          &Bsm[buf][(kh) * 4 + 2 + kcS][rowS][0]);                            \
  } while (0)

#define MFMA16(mb) do {                                                       \
    if constexpr (VAR == 0) {                                                 \
      __builtin_amdgcn_s_setprio(1);                                          \
      _Pragma("unroll")                                                       \
      for (int m = 0; m < 4; ++m) {                                           \
        _Pragma("unroll")                                                     \
        for (int n = 0; n < 4; ++n)                                           \
          acc[(mb) + m][n] = __builtin_amdgcn_mfma_f32_16x16x32_bf16(         \
              af[m], bf[n], acc[(mb) + m][n], 0, 0, 0);                       \
      }                                                                       \
      __builtin_amdgcn_s_setprio(0);                                          \
    } else if constexpr (VAR == 2) {                                          \
      asm volatile("" :: "v"(af[0]), "v"(af[1]), "v"(af[2]), "v"(af[3]),      \
                          "v"(bf[0]), "v"(bf[1]), "v"(bf[2]), "v"(bf[3]));    \
    }                                                                         \
  } while (0)

#define BARF()  do { asm volatile("s_barrier" ::: "memory");                  \
                     __builtin_amdgcn_sched_barrier(0); } while (0)
#define LKW0()  do { if constexpr (VAR != 1)                                  \
                     asm volatile("s_waitcnt lgkmcnt(0)" ::: "memory"); } while (0)
#define VMW(n)  asm volatile("s_waitcnt vmcnt(" #n ")" ::: "memory")

  const int fr = lane & 15, fk = lane >> 4;
  const int NT = NTRUN;

  SA(0, 0, 0); SB(0, 0, 0); SA(0, 0, 1); SB(0, 0, 1);
  SA(1, 1, 0); SB(1, 1, 0);
  VMW(8);
  BARF();

  bf16x8 af[4], bf[4];

  for (int tt = 0; tt < NT; ++tt) {
    const int c = tt & 1;
    const int t1 = (tt + 1 < NT) ? tt + 1 : NT - 1;
    const int t2 = (tt + 2 < NT) ? tt + 2 : NT - 1;

    // ---- P0 ----
    SA(c ^ 1, t1, 1);
    if constexpr (VAR != 1) {
      #pragma unroll
      for (int m = 0; m < 4; ++m)
        af[m] = *(const bf16x8*)&Asm[c][fk][wr * 128 + m * 16 + fr][0];
      #pragma unroll
      for (int n = 0; n < 4; ++n)
        bf[n] = *(const bf16x8*)&Bsm[c][fk][wc * 64 + n * 16 + fr][0];
    }
    LKW0();
    BARF();
    MFMA16(0);

    // ---- P1 ----
    SB(c ^ 1, t1, 1);
    if constexpr (VAR != 1) {
      #pragma unroll
      for (int m = 0; m < 4; ++m)
        af[m] = *(const bf16x8*)&Asm[c][fk][wr * 128 + (m + 4) * 16 + fr][0];
    }
    LKW0();
    VMW(8);
    BARF();
    MFMA16(4);

    // ---- P2 ----
    SA(c, t2, 0);
    if constexpr (VAR != 1) {
      #pragma unroll
      for (int m = 0; m < 4; ++m)
        af[m] = *(const bf16x8*)&Asm[c][4 + fk][wr * 128 + m * 16 + fr][0];
      #pragma unroll
      for (int n = 0; n < 4; ++n)
        bf[n] = *(const bf16x8*)&Bsm[c][4 + fk][wc * 64 + n * 16 + fr][0];
    }
    LKW0();
    BARF();
    MFMA16(0);

    // ---- P3 ----
    SB(c, t2, 0);
    if constexpr (VAR != 1) {
      #pragma unroll
      for (int m = 0; m < 4; ++m)
        af[m] = *(const bf16x8*)&Asm[c][4 + fk][wr * 128 + (m + 4) * 16 + fr][0];
    }
    LKW0();
    VMW(8);
    BARF();
    MFMA16(4);
  }
  VMW(0);
#undef SA
#undef SB
#undef MFMA16
#undef BARF
#undef LKW0
#undef VMW

  // epilogue (kept in all variants for identical shape; probes write garbage
  // that the final VAR=0 dispatch overwrites)
  const int fq = lane >> 4;
  #pragma unroll
  for (int m = 0; m < 8; ++m) {
    #pragma unroll
    for (int n = 0; n < 4; ++n) {
      int col = n0 + wc * 64 + n * 16 + fr;
      int rowb = m0 + wr * 128 + m * 16 + fq * 4;
      #pragma unroll
      for (int j = 0; j < 4; ++j)
        C[(size_t)(rowb + j) * NCOLS + col] = f2b(acc[m][n][j]);
    }
  }
}

// ---------- kernel 4: windowed softmax + halves-sum + RMSNorm + RoPE + scatter ----------
__device__ inline float soft_half(const bf16x8* scv, const bf16x8* kvv,
                                  const float ap[4][8], const bool valid[4], int i) {
  float sc[4];
  #pragma unroll
  for (int r = 0; r < 4; ++r)
    sc[r] = valid[r] ? b2f((u16)scv[r][i]) : -1e30f;
  float m = fmaxf(fmaxf(sc[0], sc[1]), fmaxf(sc[2], sc[3]));
  float e[4], sum = 0.f;
  #pragma unroll
  for (int r = 0; r < 4; ++r) { e[r] = __expf(sc[r] - m); sum += e[r]; }
  float inv = 1.0f / sum;
  float o = 0.f;
  #pragma unroll
  for (int r = 0; r < 4; ++r)
    o += e[r] * (b2f((u16)kvv[r][i]) + ap[r][i]);
  return o * inv;
}

__global__ __launch_bounds__(256) void fuse_kernel(const u16* __restrict__ kvsc,
                                                   const float* __restrict__ ape,
                                                   const float* __restrict__ norm_w,
                                                   const float* __restrict__ cosb,
                                                   const float* __restrict__ sinb,
                                                   const int* __restrict__ bo,
                                                   float* __restrict__ ckv_out,
                                                   float* __restrict__ cache_out) {
  __shared__ float ape_s[4][1024];
  const int t = threadIdx.x;
  for (int j = t; j < 1024; j += 256)
    ((float4*)&ape_s[0][0])[j] = ((const float4*)ape)[j];
  __syncthreads();

  const int wave = t >> 6, lane = t & 63;
  const int g = blockIdx.x * 4 + wave;
  const int b = g >> 12, s = g & 4095;
  const int c0 = lane * 8;

  const u16* base = kvsc + (size_t)b * SLEN * NCOLS;
  bf16x8 kv_lo[4], kv_hi[4], sc_lo[4], sc_hi[4];
  float apl[4][8], aph[4][8];
  bool valid[4];
  #pragma unroll
  for (int r = 0; r < 4; ++r) {
    int sr = s - 3 + r;
    valid[r] = (sr >= 0);
    int src = sr < 0 ? 0 : sr;
    int rot = src & 3;
    const u16* rp = base + (size_t)src * NCOLS;
    kv_lo[r] = *(const bf16x8*)(rp + c0);
    kv_hi[r] = *(const bf16x8*)(rp + 512 + c0);
    sc_lo[r] = *(const bf16x8*)(rp + 1024 + c0);
    sc_hi[r] = *(const bf16x8*)(rp + 1536 + c0);
    *(float4*)&apl[r][0] = *(const float4*)&ape_s[rot][c0];
    *(float4*)&apl[r][4] = *(const float4*)&ape_s[rot][c0 + 4];
    *(float4*)&aph[r][0] = *(const float4*)&ape_s[rot][512 + c0];
    *(float4*)&aph[r][4] = *(const float4*)&ape_s[rot][512 + c0 + 4];
  }

  float res[8];
  float sumsq = 0.f;
  #pragma unroll
  for (int i = 0; i < 8; ++i) {
    float o = soft_half(sc_lo, kv_lo, apl, valid, i) +
              soft_half(sc_hi, kv_hi, aph, valid, i);
    res[i] = o;
    sumsq += o * o;
  }
  #pragma unroll
  for (int off = 32; off > 0; off >>= 1)
    sumsq += __shfl_xor(sumsq, off, 64);
  const float scale = rsqrtf(sumsq * (1.0f / 512.0f) + 1e-6f);

  float4 nwa = *(const float4*)&norm_w[c0];
  float4 nwb = *(const float4*)&norm_w[c0 + 4];
  res[0] *= scale * nwa.x; res[1] *= scale * nwa.y;
  res[2] *= scale * nwa.z; res[3] *= scale * nwa.w;
  res[4] *= scale * nwb.x; res[5] *= scale * nwb.y;
  res[6] *= scale * nwb.z; res[7] *= scale * nwb.w;

  if (lane >= 56) {   // channels 448..511: RoPE
    int j0 = (lane - 56) * 4;
    float4 cs = *(const float4*)&cosb[(size_t)s * 32 + j0];
    float4 sn = *(const float4*)&sinb[(size_t)s * 32 + j0];
    float cc[4] = {cs.x, cs.y, cs.z, cs.w};
    float ss[4] = {sn.x, sn.y, sn.z, sn.w};
    #pragma unroll
    for (int p = 0; p < 4; ++p) {
      float cr = res[2 * p], ci = res[2 * p + 1];
      res[2 * p]     = cr * cc[p] - ci * ss[p];
      res[2 * p + 1] = cr * ss[p] + ci * cc[p];
    }
  }

  float4 v0 = make_float4(res[0], res[1], res[2], res[3]);
  float4 v1 = make_float4(res[4], res[5], res[6], res[7]);
  float* op = ckv_out + (size_t)g * HD + c0;
  *(float4*)op = v0;
  *(float4*)(op + 4) = v1;

  if ((s & 3) == 3) {
    int cidx = s >> 2;
    int blk = bo[b * 16 + (cidx >> 6)];
    int off = cidx & 63;
    float* cp = cache_out + ((size_t)blk * 64 + off) * HD + c0;
    *(float4*)cp = v0;
    *(float4*)(cp + 4) = v1;
  }
}

// ---------- launch ----------
extern "C" void kernel_launch(void* const* d_in, const int* in_sizes, int n_in,
                              void* d_out, int out_size, void* d_ws, size_t ws_size,
                              hipStream_t stream) {
  const float* x    = (const float*)d_in[0];
  const float* wkv  = (const float*)d_in[1];
  const float* wg   = (const float*)d_in[2];
  const float* ape  = (const float*)d_in[3];
  const float* nw   = (const float*)d_in[4];
  const float* cosb = (const float*)d_in[5];
  const float* sinb = (const float*)d_in[6];
  const int*   bo   = (const int*)d_in[7];

  float* out = (float*)d_out;
  char* ws = (char*)d_ws;
  u16* xb   = (u16*)ws;                                              // 128 MiB
  u16* Wt   = (u16*)(ws + (size_t)MROWS * DIMK * 2);                 //  16 MiB
  u16* kvsc = (u16*)(ws + (size_t)MROWS * DIMK * 2 + (size_t)NCOLS * DIMK * 2); // 64 MiB

  hipLaunchKernelGGL(cvt_x_kernel, dim3(32768), dim3(256), 0, stream,
                     (const float4*)x, xb);
  hipLaunchKernelGGL(build_wt_kernel, dim3(32, 64), dim3(256), 0, stream, wkv, wg, Wt);

  // --- ablation probes (NTRUN=256 = 4x K; garbage output, overwritten) ---
  hipLaunchKernelGGL((gemm_probe<1, 256>), dim3(512), dim3(512), 0, stream, xb, Wt, kvsc);
  hipLaunchKernelGGL((gemm_probe<2, 256>), dim3(512), dim3(512), 0, stream, xb, Wt, kvsc);

  // --- correct GEMM (final write wins) ---
  hipLaunchKernelGGL((gemm_probe<0, 64>), dim3(512), dim3(512), 0, stream, xb, Wt, kvsc);

  float* ckv_out = out;
  float* cache_out = out + (size_t)MROWS * HD;
  hipMemsetAsync(cache_out, 0, (size_t)64 * 64 * HD * sizeof(float), stream);
  hipLaunchKernelGGL(fuse_kernel, dim3(MROWS / 4), dim3(256), 0, stream,
                     kvsc, ape, nw, cosb, sinb, bo, ckv_out, cache_out);
}

// Round 9
// 509.398 us; speedup vs baseline: 5.9451x; 5.9451x over previous
//
#include <hip/hip_runtime.h>

// Problem constants (match reference)
#define BATCH 4
#define SLEN  4096
#define DIMK  4096
#define HD    512
#define RD    64
#define NCOLS 2048          // [kv(1024) | sc(1024)]
#define MROWS (BATCH*SLEN)  // 16384

typedef __attribute__((ext_vector_type(8))) short bf16x8;
typedef __attribute__((ext_vector_type(4))) float f32x4;
typedef unsigned short u16;

// ---------- bf16 helpers ----------
__device__ inline u16 f2b(float f) {
  union { float f; unsigned u; } x; x.f = f;
  unsigned r = (x.u + 0x7fffu + ((x.u >> 16) & 1u)) >> 16;
  return (u16)r;
}
__device__ inline float b2f(u16 u) {
  union { float f; unsigned u; } x; x.u = ((unsigned)u) << 16; return x.f;
}

#define GLL16(gp, lp) __builtin_amdgcn_global_load_lds( \
    (__attribute__((address_space(1))) void*)(gp),      \
    (__attribute__((address_space(3))) void*)(lp), 16, 0, 0)

// ---------- kernel 1: x (f32) -> bf16 ----------
__global__ __launch_bounds__(256) void cvt_x_kernel(const float4* __restrict__ x,
                                                    u16* __restrict__ xb) {
  size_t i = (size_t)blockIdx.x * 256 + threadIdx.x;
  float4 a = x[2 * i], b = x[2 * i + 1];
  bf16x8 v;
  v[0] = (short)f2b(a.x); v[1] = (short)f2b(a.y);
  v[2] = (short)f2b(a.z); v[3] = (short)f2b(a.w);
  v[4] = (short)f2b(b.x); v[5] = (short)f2b(b.y);
  v[6] = (short)f2b(b.z); v[7] = (short)f2b(b.w);
  *(bf16x8*)(xb + i * 8) = v;
}

// ---------- kernel 2: Wt[n][k] = [wkv|wgate][k][n] as bf16 ----------
__global__ __launch_bounds__(256) void build_wt_kernel(const float* __restrict__ wkv,
                                                       const float* __restrict__ wg,
                                                       u16* __restrict__ Wt) {
  __shared__ u16 tile[64][72];
  const int n0 = blockIdx.x * 64;
  const int k0 = blockIdx.y * 64;
  const float* src = (n0 < 1024) ? wkv : wg;
  const int nbase = (n0 < 1024) ? n0 : (n0 - 1024);
  const int t = threadIdx.x;
  const int nn = t & 63, kq = t >> 6;
  #pragma unroll
  for (int j = 0; j < 16; ++j) {
    int k = kq + j * 4;
    float v = src[(size_t)(k0 + k) * 1024 + nbase + nn];
    tile[nn][k] = f2b(v);
  }
  __syncthreads();
  const int kk8 = (t & 7) * 8;
  #pragma unroll
  for (int j = 0; j < 2; ++j) {
    int nn2 = (t >> 3) + j * 32;
    bf16x8 v = *(bf16x8*)&tile[nn2][kk8];
    *(bf16x8*)&Wt[(size_t)(n0 + nn2) * DIMK + k0 + kk8] = v;
  }
}

// ---------- kernel 3: GEMM 256x256, BK=32, ring-3, COALESCED staging ----------
// R8 ablation: staging = 79% of kernel; ds_reads free. Root cause: k-chunk-major
// LDS made GLL's global side 64-lane-scattered (64 lines/instr). Fix: row-major
// LDS [256][32] (rows = 64B, 16 segments/GLL = 4x fewer requests) with XOR
// swizzle X(row) = (row&3)^((row>>2)&3) applied to BOTH the GLL global source
// (per-lane pre-swizzle, m173) and the ds_read address (rule #21) -> ~2-way
// bank spread. Ring-3 buffers, 2-tile-deep prefetch, VMW(4) steady ledger.
// Phase = {stage 2 GLL; 8 ds_read; lgkm0; BAR; sched_barrier; 16 MFMA}.
__global__ __launch_bounds__(512, 2) void gemm_kernel(const u16* __restrict__ A,
                                                      const u16* __restrict__ Bt,
                                                      u16* __restrict__ C) {
  __shared__ __align__(16) u16 Asm[3][256][32];     // 48 KiB
  __shared__ __align__(16) u16 Bsm[3][256][32];     // 48 KiB
  const int t = threadIdx.x;
  const int lane = t & 63, wave = t >> 6;

  // XCD chunked swizzle: nwg=512, 64 contiguous logical blocks per XCD.
  const int orig = blockIdx.x;
  const int lid = (orig & 7) * 64 + (orig >> 3);
  const int mt = lid >> 3, nt = lid & 7;            // nt fast: 8 share A panel
  const int m0 = mt * 256, n0 = nt * 256;
  const int wr = wave >> 2, wc = wave & 3;          // 2M x 4N waves

  f32x4 acc[8][4] = {};

  // ---- staging maps: one stage = 128 rows x 32k = 8 KB = 1 GLL/thread ----
  // thread t covers (rowT = t>>2, colT = t&3); LDS byte off = t*16 (linear ✓).
  // global col pre-swizzled: colX = colT ^ X(rowT), X(r) = (r&3)^((r>>2)&3).
  const int rowT = t >> 2, colT = t & 3;
  const int colX = colT ^ (rowT & 3) ^ ((rowT >> 2) & 3);
  const u16* gA0 = A  + (size_t)(m0 + rowT) * DIMK + colX * 8;
  const u16* gB0 = Bt + (size_t)(n0 + rowT) * DIMK + colX * 8;
  u16* AsmF = &Asm[0][0][0];
  u16* BsmF = &Bsm[0][0][0];
  u16* lA0 = AsmF + rowT * 32 + colT * 8;
  u16* lB0 = BsmF + rowT * 32 + colT * 8;

#define SA(buf, tt, h) GLL16(gA0 + (size_t)((h) * 128) * DIMK + (tt) * 32, \
                             lA0 + (buf) * 8192 + (h) * 4096)
#define SB(buf, tt, h) GLL16(gB0 + (size_t)((h) * 128) * DIMK + (tt) * 32, \
                             lB0 + (buf) * 8192 + (h) * 4096)

#define MFMA16(mb) do {                                                       \
    __builtin_amdgcn_s_setprio(1);                                            \
    _Pragma("unroll")                                                         \
    for (int m = 0; m < 4; ++m) {                                             \
      _Pragma("unroll")                                                       \
      for (int n = 0; n < 4; ++n)                                             \
        acc[(mb) + m][n] = __builtin_amdgcn_mfma_f32_16x16x32_bf16(           \
            af[m], bf[n], acc[(mb) + m][n], 0, 0, 0);                         \
    }                                                                         \
    __builtin_amdgcn_s_setprio(0);                                            \
  } while (0)

#define BARF()  do { asm volatile("s_barrier" ::: "memory");                  \
                     __builtin_amdgcn_sched_barrier(0); } while (0)
#define LKW0()  asm volatile("s_waitcnt lgkmcnt(0)" ::: "memory")

  // ---- fragment-read addressing (swizzled) ----
  // af[m]: row = wr*128 + m*16 + fr, k-slot fk; X(row) = (fr&3)^((fr>>2)&3).
  const int fr = lane & 15, fk = lane >> 4;
  const int fkx = (fk ^ (fr & 3) ^ ((fr >> 2) & 3)) * 8;  // swizzled 16B slot
  const int NT = DIMK / 32;                          // 128 K-tiles

  // prologue: tiles 0 and 1 fully staged (8 GLL/thread)
  SA(0, 0, 0); SA(0, 0, 1); SB(0, 0, 0); SB(0, 0, 1);
  SA(1, 1, 0); SA(1, 1, 1); SB(1, 1, 0); SB(1, 1, 1);
  asm volatile("s_waitcnt vmcnt(4)" ::: "memory");   // tile 0 landed
  BARF();

  bf16x8 af[4], bf[4];

  for (int tt = 0; tt < NT; ++tt) {
    const int cb = tt % 3;
    const int wb = (tt + 2) % 3;
    const bool st = (tt + 2 < NT);                   // wave-uniform

    // ---- P0: stage A(tt+2); read m0-3 + B; MFMA ----
    if (st) { SA(wb, tt + 2, 0); SA(wb, tt + 2, 1); }
    #pragma unroll
    for (int m = 0; m < 4; ++m)
      af[m] = *(const bf16x8*)(AsmF + cb * 8192 + (wr * 128 + m * 16 + fr) * 32 + fkx);
    #pragma unroll
    for (int n = 0; n < 4; ++n)
      bf[n] = *(const bf16x8*)(BsmF + cb * 8192 + (wc * 64 + n * 16 + fr) * 32 + fkx);
    LKW0();
    BARF();
    MFMA16(0);

    // ---- P1: stage B(tt+2); read m4-7 (bf reused); counted vmcnt; MFMA ----
    if (st) { SB(wb, tt + 2, 0); SB(wb, tt + 2, 1); }
    #pragma unroll
    for (int m = 0; m < 4; ++m)
      af[m] = *(const bf16x8*)(AsmF + cb * 8192 + (wr * 128 + (m + 4) * 16 + fr) * 32 + fkx);
    LKW0();
    if (tt < NT - 2) asm volatile("s_waitcnt vmcnt(4)" ::: "memory"); // tile tt+1 landed
    else             asm volatile("s_waitcnt vmcnt(0)" ::: "memory"); // tail drain
    BARF();
    MFMA16(4);
  }
#undef SA
#undef SB
#undef MFMA16
#undef BARF
#undef LKW0

  // epilogue: C/D layout col=lane&15, row=(lane>>4)*4+j (m89-verified)
  const int fq = lane >> 4;
  #pragma unroll
  for (int m = 0; m < 8; ++m) {
    #pragma unroll
    for (int n = 0; n < 4; ++n) {
      int col = n0 + wc * 64 + n * 16 + fr;
      int rowb = m0 + wr * 128 + m * 16 + fq * 4;
      #pragma unroll
      for (int j = 0; j < 4; ++j)
        C[(size_t)(rowb + j) * NCOLS + col] = f2b(acc[m][n][j]);
    }
  }
}

// ---------- kernel 4: windowed softmax + halves-sum + RMSNorm + RoPE + scatter ----------
__device__ inline float soft_half(const bf16x8* scv, const bf16x8* kvv,
                                  const float ap[4][8], const bool valid[4], int i) {
  float sc[4];
  #pragma unroll
  for (int r = 0; r < 4; ++r)
    sc[r] = valid[r] ? b2f((u16)scv[r][i]) : -1e30f;
  float m = fmaxf(fmaxf(sc[0], sc[1]), fmaxf(sc[2], sc[3]));
  float e[4], sum = 0.f;
  #pragma unroll
  for (int r = 0; r < 4; ++r) { e[r] = __expf(sc[r] - m); sum += e[r]; }
  float inv = 1.0f / sum;
  float o = 0.f;
  #pragma unroll
  for (int r = 0; r < 4; ++r)
    o += e[r] * (b2f((u16)kvv[r][i]) + ap[r][i]);
  return o * inv;
}

__global__ __launch_bounds__(256) void fuse_kernel(const u16* __restrict__ kvsc,
                                                   const float* __restrict__ ape,
                                                   const float* __restrict__ norm_w,
                                                   const float* __restrict__ cosb,
                                                   const float* __restrict__ sinb,
                                                   const int* __restrict__ bo,
                                                   float* __restrict__ ckv_out,
                                                   float* __restrict__ cache_out) {
  __shared__ float ape_s[4][1024];
  const int t = threadIdx.x;
  for (int j = t; j < 1024; j += 256)
    ((float4*)&ape_s[0][0])[j] = ((const float4*)ape)[j];
  __syncthreads();

  const int wave = t >> 6, lane = t & 63;
  const int g = blockIdx.x * 4 + wave;
  const int b = g >> 12, s = g & 4095;
  const int c0 = lane * 8;

  const u16* base = kvsc + (size_t)b * SLEN * NCOLS;
  bf16x8 kv_lo[4], kv_hi[4], sc_lo[4], sc_hi[4];
  float apl[4][8], aph[4][8];
  bool valid[4];
  #pragma unroll
  for (int r = 0; r < 4; ++r) {
    int sr = s - 3 + r;
    valid[r] = (sr >= 0);
    int src = sr < 0 ? 0 : sr;
    int rot = src & 3;
    const u16* rp = base + (size_t)src * NCOLS;
    kv_lo[r] = *(const bf16x8*)(rp + c0);
    kv_hi[r] = *(const bf16x8*)(rp + 512 + c0);
    sc_lo[r] = *(const bf16x8*)(rp + 1024 + c0);
    sc_hi[r] = *(const bf16x8*)(rp + 1536 + c0);
    *(float4*)&apl[r][0] = *(const float4*)&ape_s[rot][c0];
    *(float4*)&apl[r][4] = *(const float4*)&ape_s[rot][c0 + 4];
    *(float4*)&aph[r][0] = *(const float4*)&ape_s[rot][512 + c0];
    *(float4*)&aph[r][4] = *(const float4*)&ape_s[rot][512 + c0 + 4];
  }

  float res[8];
  float sumsq = 0.f;
  #pragma unroll
  for (int i = 0; i < 8; ++i) {
    float o = soft_half(sc_lo, kv_lo, apl, valid, i) +
              soft_half(sc_hi, kv_hi, aph, valid, i);
    res[i] = o;
    sumsq += o * o;
  }
  #pragma unroll
  for (int off = 32; off > 0; off >>= 1)
    sumsq += __shfl_xor(sumsq, off, 64);
  const float scale = rsqrtf(sumsq * (1.0f / 512.0f) + 1e-6f);

  float4 nwa = *(const float4*)&norm_w[c0];
  float4 nwb = *(const float4*)&norm_w[c0 + 4];
  res[0] *= scale * nwa.x; res[1] *= scale * nwa.y;
  res[2] *= scale * nwa.z; res[3] *= scale * nwa.w;
  res[4] *= scale * nwb.x; res[5] *= scale * nwb.y;
  res[6] *= scale * nwb.z; res[7] *= scale * nwb.w;

  if (lane >= 56) {   // channels 448..511: RoPE
    int j0 = (lane - 56) * 4;
    float4 cs = *(const float4*)&cosb[(size_t)s * 32 + j0];
    float4 sn = *(const float4*)&sinb[(size_t)s * 32 + j0];
    float cc[4] = {cs.x, cs.y, cs.z, cs.w};
    float ss[4] = {sn.x, sn.y, sn.z, sn.w};
    #pragma unroll
    for (int p = 0; p < 4; ++p) {
      float cr = res[2 * p], ci = res[2 * p + 1];
      res[2 * p]     = cr * cc[p] - ci * ss[p];
      res[2 * p + 1] = cr * ss[p] + ci * cc[p];
    }
  }

  float4 v0 = make_float4(res[0], res[1], res[2], res[3]);
  float4 v1 = make_float4(res[4], res[5], res[6], res[7]);
  float* op = ckv_out + (size_t)g * HD + c0;
  *(float4*)op = v0;
  *(float4*)(op + 4) = v1;

  if ((s & 3) == 3) {
    int cidx = s >> 2;
    int blk = bo[b * 16 + (cidx >> 6)];
    int off = cidx & 63;
    float* cp = cache_out + ((size_t)blk * 64 + off) * HD + c0;
    *(float4*)cp = v0;
    *(float4*)(cp + 4) = v1;
  }
}

// ---------- launch ----------
extern "C" void kernel_launch(void* const* d_in, const int* in_sizes, int n_in,
                              void* d_out, int out_size, void* d_ws, size_t ws_size,
                              hipStream_t stream) {
  const float* x    = (const float*)d_in[0];
  const float* wkv  = (const float*)d_in[1];
  const float* wg   = (const float*)d_in[2];
  const float* ape  = (const float*)d_in[3];
  const float* nw   = (const float*)d_in[4];
  const float* cosb = (const float*)d_in[5];
  const float* sinb = (const float*)d_in[6];
  const int*   bo   = (const int*)d_in[7];

  float* out = (float*)d_out;
  char* ws = (char*)d_ws;
  u16* xb   = (u16*)ws;                                              // 128 MiB
  u16* Wt   = (u16*)(ws + (size_t)MROWS * DIMK * 2);                 //  16 MiB
  u16* kvsc = (u16*)(ws + (size_t)MROWS * DIMK * 2 + (size_t)NCOLS * DIMK * 2); // 64 MiB

  hipLaunchKernelGGL(cvt_x_kernel, dim3(32768), dim3(256), 0, stream,
                     (const float4*)x, xb);
  hipLaunchKernelGGL(build_wt_kernel, dim3(32, 64), dim3(256), 0, stream, wkv, wg, Wt);
  hipLaunchKernelGGL(gemm_kernel, dim3(512), dim3(512), 0, stream, xb, Wt, kvsc);

  float* ckv_out = out;
  float* cache_out = out + (size_t)MROWS * HD;
  hipMemsetAsync(cache_out, 0, (size_t)64 * 64 * HD * sizeof(float), stream);
  hipLaunchKernelGGL(fuse_kernel, dim3(MROWS / 4), dim3(256), 0, stream,
                     kvsc, ape, nw, cosb, sinb, bo, ckv_out, cache_out);
}